// Round 1
// baseline (715.170 us; speedup 1.0000x reference)
//
#include <hip/hip_runtime.h>
#include <hip/hip_bf16.h>

// ---------------------------------------------------------------------------
// GraphSAGE (2x SAGEConv mean + linear head), fp32, MI355X.
// Pipeline per call (all on `stream`, graph-capture safe):
//   detect ei dtype -> convert to int32 -> degree -> scan(rowptr) -> scatter(CSR)
//   agg1(mean of x) -> gemm1(h1 = relu(agg1@W1l + x@W1r + b1))
//   agg2(mean of h1) -> gemm2(h2 = relu(agg2@W2l + h1@W2r + b2))
//   gemm_final(out = h2@Wc + bc)
// ---------------------------------------------------------------------------

#define F_IN 128
#define H1_DIM 256
#define H2_DIM 256
#define C_DIM 64

// ---------------- edge-index dtype detection + conversion ------------------
// If the buffer is int64, every odd 32-bit word (high half) is 0 (values <
// 50000). If int32, odd words are random node ids; P(128 zeros) ~ 0.
__global__ void k_detect(const unsigned int* __restrict__ ei, int* __restrict__ flag) {
    if (blockIdx.x == 0 && threadIdx.x == 0) {
        int is64 = 1;
        for (int i = 1; i < 256; i += 2) {
            if (ei[i] != 0u) { is64 = 0; break; }
        }
        *flag = is64;
    }
}

__global__ void k_convert(const void* __restrict__ ei, const int* __restrict__ flag,
                          int* __restrict__ out, int n2e) {
    int i = blockIdx.x * blockDim.x + threadIdx.x;
    if (i >= n2e) return;
    if (*flag) out[i] = (int)((const long long*)ei)[i];
    else       out[i] = ((const int*)ei)[i];
}

// ---------------- CSR build ------------------------------------------------
__global__ void k_degree(const int* __restrict__ ei32, int* __restrict__ cnt, int E) {
    int i = blockIdx.x * blockDim.x + threadIdx.x;
    if (i >= E) return;
    atomicAdd(&cnt[ei32[E + i]], 1);
}

// 3-kernel exclusive scan of cnt[n] -> rowptr[n+1]
__global__ void k_scan1(const int* __restrict__ cnt, int* __restrict__ rowptr,
                        int* __restrict__ bsum, int n) {
    __shared__ int s[256];
    int i = blockIdx.x * 256 + threadIdx.x;
    int v = (i < n) ? cnt[i] : 0;
    s[threadIdx.x] = v;
    __syncthreads();
    for (int off = 1; off < 256; off <<= 1) {
        int t = (threadIdx.x >= off) ? s[threadIdx.x - off] : 0;
        __syncthreads();
        s[threadIdx.x] += t;
        __syncthreads();
    }
    if (i < n) rowptr[i] = s[threadIdx.x] - v;   // exclusive within block
    if (threadIdx.x == 255) bsum[blockIdx.x] = s[255];
}

__global__ void k_scan2(const int* __restrict__ bsum, int* __restrict__ boff, int nb) {
    __shared__ int s[1024];
    int t = threadIdx.x;
    int v = (t < nb) ? bsum[t] : 0;
    s[t] = v;
    __syncthreads();
    for (int off = 1; off < 1024; off <<= 1) {
        int u = (t >= off) ? s[t - off] : 0;
        __syncthreads();
        s[t] += u;
        __syncthreads();
    }
    if (t < nb) boff[t] = s[t] - v;
}

__global__ void k_scan3(int* __restrict__ rowptr, const int* __restrict__ boff,
                        int n, int total) {
    int i = blockIdx.x * 256 + threadIdx.x;
    if (i < n) rowptr[i] += boff[i >> 8];
    if (i == 0) rowptr[n] = total;
}

__global__ void k_scatter(const int* __restrict__ ei32, const int* __restrict__ rowptr,
                          int* __restrict__ pos, int* __restrict__ col, int E) {
    int i = blockIdx.x * blockDim.x + threadIdx.x;
    if (i >= E) return;
    int s = ei32[i];
    int d = ei32[E + i];
    int p = atomicAdd(&pos[d], 1);
    col[rowptr[d] + p] = s;
}

// ---------------- aggregation: wave-per-node segment mean ------------------
template <int CH>
__global__ void k_agg(const float* __restrict__ feat, const int* __restrict__ rowptr,
                      const int* __restrict__ col, float* __restrict__ outmean, int n) {
    int w = blockIdx.x * (blockDim.x >> 6) + (threadIdx.x >> 6);
    int lane = threadIdx.x & 63;
    if (w >= n) return;
    int beg = rowptr[w], end = rowptr[w + 1];
    float inv = 1.0f / fmaxf((float)(end - beg), 1.0f);
    if constexpr (CH == 128) {
        float2 acc = make_float2(0.f, 0.f);
        for (int j = beg; j < end; ++j) {
            const float2* row = (const float2*)(feat + (size_t)col[j] * CH);
            float2 v = row[lane];
            acc.x += v.x; acc.y += v.y;
        }
        float2 r = make_float2(acc.x * inv, acc.y * inv);
        ((float2*)(outmean + (size_t)w * CH))[lane] = r;
    } else {
        float4 acc = make_float4(0.f, 0.f, 0.f, 0.f);
        for (int j = beg; j < end; ++j) {
            const float4* row = (const float4*)(feat + (size_t)col[j] * CH);
            float4 v = row[lane];
            acc.x += v.x; acc.y += v.y; acc.z += v.z; acc.w += v.w;
        }
        float4 r = make_float4(acc.x * inv, acc.y * inv, acc.z * inv, acc.w * inv);
        ((float4*)(outmean + (size_t)w * CH))[lane] = r;
    }
}

// ---------------- fp32 tiled GEMM, two fused A-sources ---------------------
// C[M,NN] = act(A1[M,K1]@B1[K1,NN] (+ A2[M,K2]@B2[K2,NN]) + bias)
// BM=128, BK=16, 256 threads, per-thread 8 x (4*NJG) split micro-tile.
template <int BN, bool TWO, bool RELU>
__global__ __launch_bounds__(256, 2) void k_gemm(
    const float* __restrict__ A1, const float* __restrict__ B1, int K1,
    const float* __restrict__ A2, const float* __restrict__ B2, int K2,
    const float* __restrict__ bias, float* __restrict__ C, int M, int NN) {
    constexpr int BM = 128, BK = 16;
    constexpr int NJG = BN / 64;   // column groups of 64
    int nbn = NN / BN;
    int bm = blockIdx.x / nbn;
    int bn = blockIdx.x % nbn;
    int row0 = bm * BM, col0 = bn * BN;

    __shared__ float As[BK][BM + 4];
    __shared__ float Bs[BK][BN + 4];

    int tid = threadIdx.x;
    int tx = tid & 15, ty = tid >> 4;

    float acc[8][4 * NJG];
#pragma unroll
    for (int i = 0; i < 8; ++i)
#pragma unroll
        for (int j = 0; j < 4 * NJG; ++j) acc[i][j] = 0.f;

    int Ktot = TWO ? (K1 + K2) : K1;
    for (int k0 = 0; k0 < Ktot; k0 += BK) {
        const float* A; const float* B; int K; int kk;
        if (!TWO || k0 < K1) { A = A1; B = B1; K = K1; kk = k0; }
        else                 { A = A2; B = B2; K = K2; kk = k0 - K1; }

        // stage A tile (BM x BK), transposed into As[k][row]
#pragma unroll
        for (int t = 0; t < (BM * BK) / (256 * 4); ++t) {
            int chunk = tid + t * 256;
            int r = chunk >> 2;            // BK/4 = 4 float4 per row
            int c4 = (chunk & 3) * 4;
            int gr = row0 + r;
            float4 v = make_float4(0.f, 0.f, 0.f, 0.f);
            if (gr < M) v = *(const float4*)(A + (size_t)gr * K + kk + c4);
            As[c4 + 0][r] = v.x;
            As[c4 + 1][r] = v.y;
            As[c4 + 2][r] = v.z;
            As[c4 + 3][r] = v.w;
        }
        // stage B tile (BK x BN)
#pragma unroll
        for (int t = 0; t < (BK * BN) / (256 * 4); ++t) {
            int chunk = tid + t * 256;
            int r = chunk / (BN / 4);
            int c4 = (chunk % (BN / 4)) * 4;
            float4 v = *(const float4*)(B + (size_t)(kk + r) * NN + col0 + c4);
            *(float4*)&Bs[r][c4] = v;
        }
        __syncthreads();

#pragma unroll
        for (int k = 0; k < BK; ++k) {
            float a[8], b[4 * NJG];
            *(float4*)&a[0] = *(const float4*)&As[k][ty * 4];
            *(float4*)&a[4] = *(const float4*)&As[k][64 + ty * 4];
#pragma unroll
            for (int g = 0; g < NJG; ++g)
                *(float4*)&b[g * 4] = *(const float4*)&Bs[k][g * 64 + tx * 4];
#pragma unroll
            for (int i = 0; i < 8; ++i)
#pragma unroll
                for (int j = 0; j < 4 * NJG; ++j)
                    acc[i][j] = fmaf(a[i], b[j], acc[i][j]);
        }
        __syncthreads();
    }

    // epilogue: bias (+ relu), float4 stores
#pragma unroll
    for (int i = 0; i < 8; ++i) {
        int r = row0 + ((i < 4) ? (ty * 4 + i) : (64 + ty * 4 + (i - 4)));
        if (r >= M) continue;
#pragma unroll
        for (int g = 0; g < NJG; ++g) {
            int cc = col0 + g * 64 + tx * 4;
            float4 v;
            v.x = acc[i][g * 4 + 0] + bias[cc + 0];
            v.y = acc[i][g * 4 + 1] + bias[cc + 1];
            v.z = acc[i][g * 4 + 2] + bias[cc + 2];
            v.w = acc[i][g * 4 + 3] + bias[cc + 3];
            if (RELU) {
                v.x = fmaxf(v.x, 0.f); v.y = fmaxf(v.y, 0.f);
                v.z = fmaxf(v.z, 0.f); v.w = fmaxf(v.w, 0.f);
            }
            *(float4*)(C + (size_t)r * NN + cc) = v;
        }
    }
}

// ---------------------------------------------------------------------------
extern "C" void kernel_launch(void* const* d_in, const int* in_sizes, int n_in,
                              void* d_out, int out_size, void* d_ws, size_t ws_size,
                              hipStream_t stream) {
    const float* x   = (const float*)d_in[0];
    const void*  ei  = d_in[1];
    const float* W1l = (const float*)d_in[2];
    const float* b1  = (const float*)d_in[3];
    const float* W1r = (const float*)d_in[4];
    const float* W2l = (const float*)d_in[5];
    const float* b2  = (const float*)d_in[6];
    const float* W2r = (const float*)d_in[7];
    const float* Wc  = (const float*)d_in[8];
    const float* bc  = (const float*)d_in[9];
    float* out = (float*)d_out;

    const int N = in_sizes[0] / F_IN;     // 50000
    const int E = in_sizes[1] / 2;        // 800000

    // ---- workspace carve-up (256B aligned) ----
    char* w = (char*)d_ws;
    size_t off = 0;
    auto carve = [&](size_t bytes) -> char* {
        char* p = w + off;
        off = (off + bytes + 255) & ~(size_t)255;
        return p;
    };
    int*   ei32   = (int*)carve((size_t)2 * E * 4);
    int*   cnt    = (int*)carve((size_t)N * 4);
    int*   pos    = (int*)carve((size_t)N * 4);
    int*   rowptr = (int*)carve((size_t)(N + 1) * 4);
    int*   bsum   = (int*)carve(1024 * 4);
    int*   boff   = (int*)carve(1024 * 4);
    int*   flag   = (int*)carve(256);
    int*   col    = (int*)carve((size_t)E * 4);
    float* agg    = (float*)carve((size_t)N * 256 * 4);
    float* h1     = (float*)carve((size_t)N * 256 * 4);
    float* h2     = (float*)carve((size_t)N * 256 * 4);
    (void)ws_size;

    // zero cnt..pos range (contiguous carves; zeroing pad is harmless)
    hipMemsetAsync(cnt, 0, (char*)rowptr - (char*)cnt, stream);

    // ---- CSR build ----
    k_detect<<<1, 64, 0, stream>>>((const unsigned int*)ei, flag);
    k_convert<<<(2 * E + 255) / 256, 256, 0, stream>>>(ei, flag, ei32, 2 * E);
    k_degree<<<(E + 255) / 256, 256, 0, stream>>>(ei32, cnt, E);
    int nb = (N + 255) / 256;
    k_scan1<<<nb, 256, 0, stream>>>(cnt, rowptr, bsum, N);
    k_scan2<<<1, 1024, 0, stream>>>(bsum, boff, nb);
    k_scan3<<<nb, 256, 0, stream>>>(rowptr, boff, N, E);
    k_scatter<<<(E + 255) / 256, 256, 0, stream>>>(ei32, rowptr, pos, col, E);

    // ---- layer 1 ----
    k_agg<F_IN><<<(N + 3) / 4, 256, 0, stream>>>(x, rowptr, col, agg, N);
    {
        int grid = ((N + 127) / 128) * (H1_DIM / 128);
        k_gemm<128, true, true><<<grid, 256, 0, stream>>>(
            agg, W1l, F_IN, x, W1r, F_IN, b1, h1, N, H1_DIM);
    }

    // ---- layer 2 ----
    k_agg<H1_DIM><<<(N + 3) / 4, 256, 0, stream>>>(h1, rowptr, col, agg, N);
    {
        int grid = ((N + 127) / 128) * (H2_DIM / 128);
        k_gemm<128, true, true><<<grid, 256, 0, stream>>>(
            agg, W2l, H1_DIM, h1, W2r, H1_DIM, b2, h2, N, H2_DIM);
    }

    // ---- head ----
    {
        int grid = ((N + 127) / 128) * (C_DIM / 64);
        k_gemm<64, false, false><<<grid, 256, 0, stream>>>(
            h2, Wc, H2_DIM, nullptr, nullptr, 0, bc, out, N, C_DIM);
    }
}

// Round 2
// 547.334 us; speedup vs baseline: 1.3066x; 1.3066x over previous
//
#include <hip/hip_runtime.h>
#include <hip/hip_bf16.h>

// ---------------------------------------------------------------------------
// GraphSAGE (2x SAGEConv mean + linear head), MI355X.
// GEMMs via split-bf16 MFMA (C = Ahi@Bhi + Alo@Bhi + Ahi@Blo, fp32 accum).
// Hidden states stored as bf16 hi/lo pairs.
// ---------------------------------------------------------------------------

#define F_IN 128
#define H1_DIM 256
#define H2_DIM 256
#define C_DIM 64

typedef __attribute__((ext_vector_type(8))) short bf16x8;
typedef __attribute__((ext_vector_type(4))) float f32x4;

__device__ __forceinline__ unsigned short f2bf(float f) {
    unsigned u = __builtin_bit_cast(unsigned, f);
    u = (u + 0x7FFFu + ((u >> 16) & 1u)) >> 16;
    return (unsigned short)u;
}
__device__ __forceinline__ float bf2f(unsigned short h) {
    return __builtin_bit_cast(float, (unsigned)h << 16);
}

// ---------------- edge-index dtype detection + conversion ------------------
__global__ void k_detect(const unsigned int* __restrict__ ei, int* __restrict__ flag) {
    if (blockIdx.x == 0 && threadIdx.x == 0) {
        int is64 = 1;
        for (int i = 1; i < 256; i += 2) {
            if (ei[i] != 0u) { is64 = 0; break; }
        }
        *flag = is64;
    }
}

__global__ void k_convert(const void* __restrict__ ei, const int* __restrict__ flag,
                          int* __restrict__ out, int n2e) {
    int i = blockIdx.x * blockDim.x + threadIdx.x;
    if (i >= n2e) return;
    if (*flag) out[i] = (int)((const long long*)ei)[i];
    else       out[i] = ((const int*)ei)[i];
}

// ---------------- CSR build ------------------------------------------------
__global__ void k_degree(const int* __restrict__ ei32, int* __restrict__ cnt, int E) {
    int i = blockIdx.x * blockDim.x + threadIdx.x;
    if (i >= E) return;
    atomicAdd(&cnt[ei32[E + i]], 1);
}

__global__ void k_scan1(const int* __restrict__ cnt, int* __restrict__ rowptr,
                        int* __restrict__ bsum, int n) {
    __shared__ int s[256];
    int i = blockIdx.x * 256 + threadIdx.x;
    int v = (i < n) ? cnt[i] : 0;
    s[threadIdx.x] = v;
    __syncthreads();
    for (int off = 1; off < 256; off <<= 1) {
        int t = (threadIdx.x >= off) ? s[threadIdx.x - off] : 0;
        __syncthreads();
        s[threadIdx.x] += t;
        __syncthreads();
    }
    if (i < n) rowptr[i] = s[threadIdx.x] - v;
    if (threadIdx.x == 255) bsum[blockIdx.x] = s[255];
}

__global__ void k_scan2(const int* __restrict__ bsum, int* __restrict__ boff, int nb) {
    __shared__ int s[1024];
    int t = threadIdx.x;
    int v = (t < nb) ? bsum[t] : 0;
    s[t] = v;
    __syncthreads();
    for (int off = 1; off < 1024; off <<= 1) {
        int u = (t >= off) ? s[t - off] : 0;
        __syncthreads();
        s[t] += u;
        __syncthreads();
    }
    if (t < nb) boff[t] = s[t] - v;
}

__global__ void k_scan3(int* __restrict__ rowptr, const int* __restrict__ boff,
                        int n, int total) {
    int i = blockIdx.x * 256 + threadIdx.x;
    if (i < n) rowptr[i] += boff[i >> 8];
    if (i == 0) rowptr[n] = total;
}

__global__ void k_scatter(const int* __restrict__ ei32, const int* __restrict__ rowptr,
                          int* __restrict__ pos, int* __restrict__ col, int E) {
    int i = blockIdx.x * blockDim.x + threadIdx.x;
    if (i >= E) return;
    int s = ei32[i];
    int d = ei32[E + i];
    int p = atomicAdd(&pos[d], 1);
    col[rowptr[d] + p] = s;
}

// ---------------- prep: fp32 -> bf16 hi/lo ---------------------------------
__global__ void k_prep_x(const float* __restrict__ x, unsigned short* __restrict__ hi,
                         unsigned short* __restrict__ lo, int n4) {
    int i = blockIdx.x * 256 + threadIdx.x;
    if (i >= n4) return;
    float4 v = ((const float4*)x)[i];
    ushort4 h, l;
    h.x = f2bf(v.x); l.x = f2bf(v.x - bf2f(h.x));
    h.y = f2bf(v.y); l.y = f2bf(v.y - bf2f(h.y));
    h.z = f2bf(v.z); l.z = f2bf(v.z - bf2f(h.z));
    h.w = f2bf(v.w); l.w = f2bf(v.w - bf2f(h.w));
    ((ushort4*)hi)[i] = h;
    ((ushort4*)lo)[i] = l;
}

// W [K][NN] fp32 -> hiT/loT [NN][K] bf16
__global__ void k_prep_wT(const float* __restrict__ W, unsigned short* __restrict__ hiT,
                          unsigned short* __restrict__ loT, int K, int NN) {
    int i = blockIdx.x * 256 + threadIdx.x;
    if (i >= K * NN) return;
    int k = i / NN, n = i % NN;
    float v = W[i];
    unsigned short h = f2bf(v);
    hiT[(size_t)n * K + k] = h;
    loT[(size_t)n * K + k] = f2bf(v - bf2f(h));
}

// ---------------- aggregation ----------------------------------------------
// layer-1: mean of fp32 x rows (CH=128) -> bf16 hi/lo
__global__ void k_agg1(const float* __restrict__ x, const int* __restrict__ rowptr,
                       const int* __restrict__ col, unsigned short* __restrict__ mhi,
                       unsigned short* __restrict__ mlo, int n) {
    int w = blockIdx.x * 4 + (threadIdx.x >> 6);
    int lane = threadIdx.x & 63;
    if (w >= n) return;
    int beg = rowptr[w], end = rowptr[w + 1];
    float inv = 1.0f / fmaxf((float)(end - beg), 1.0f);
    float ax = 0.f, ay = 0.f;
    for (int j = beg; j < end; ++j) {
        float2 v = ((const float2*)(x + (size_t)col[j] * 128))[lane];
        ax += v.x; ay += v.y;
    }
    ax *= inv; ay *= inv;
    ushort2 h, l;
    h.x = f2bf(ax); l.x = f2bf(ax - bf2f(h.x));
    h.y = f2bf(ay); l.y = f2bf(ay - bf2f(h.y));
    ((ushort2*)(mhi + (size_t)w * 128))[lane] = h;
    ((ushort2*)(mlo + (size_t)w * 128))[lane] = l;
}

// layer-2: mean of bf16 hi/lo rows (CH=256) -> bf16 hi/lo
__global__ void k_agg2(const unsigned short* __restrict__ hhi,
                       const unsigned short* __restrict__ hlo,
                       const int* __restrict__ rowptr, const int* __restrict__ col,
                       unsigned short* __restrict__ mhi, unsigned short* __restrict__ mlo,
                       int n) {
    int w = blockIdx.x * 4 + (threadIdx.x >> 6);
    int lane = threadIdx.x & 63;
    if (w >= n) return;
    int beg = rowptr[w], end = rowptr[w + 1];
    float inv = 1.0f / fmaxf((float)(end - beg), 1.0f);
    float a0 = 0.f, a1 = 0.f, a2 = 0.f, a3 = 0.f;
    for (int j = beg; j < end; ++j) {
        size_t base = (size_t)col[j] * 256 + lane * 4;
        ushort4 h = *(const ushort4*)(hhi + base);
        ushort4 l = *(const ushort4*)(hlo + base);
        a0 += bf2f(h.x) + bf2f(l.x);
        a1 += bf2f(h.y) + bf2f(l.y);
        a2 += bf2f(h.z) + bf2f(l.z);
        a3 += bf2f(h.w) + bf2f(l.w);
    }
    a0 *= inv; a1 *= inv; a2 *= inv; a3 *= inv;
    ushort4 h, l;
    h.x = f2bf(a0); l.x = f2bf(a0 - bf2f(h.x));
    h.y = f2bf(a1); l.y = f2bf(a1 - bf2f(h.y));
    h.z = f2bf(a2); l.z = f2bf(a2 - bf2f(h.z));
    h.w = f2bf(a3); l.w = f2bf(a3 - bf2f(h.w));
    size_t ob = (size_t)w * 256 + lane * 4;
    *(ushort4*)(mhi + ob) = h;
    *(ushort4*)(mlo + ob) = l;
}

// ---------------- MFMA GEMM (segments of split-bf16 sources) ---------------
// C[M,NN] = act( sum_seg A_seg[M,KS] @ B_seg[KS,NN] + bias )
// A row-major [M][KS] bf16; B stored transposed [NN][KS] bf16.
// BM=128, BK=64, 256 threads = 4 waves as 2x2, wave tile 64 x (BN/2).
struct Segs {
    const unsigned short* a[6];
    const unsigned short* b[6];
};

template <int BN, int NSEG, int KS, bool RELU, int OUTMODE>
__global__ void k_mfma_gemm(Segs segs, const float* __restrict__ bias,
                            float* __restrict__ Cf, unsigned short* __restrict__ Chi,
                            unsigned short* __restrict__ Clo, int M, int NN) {
    constexpr int BM = 128;
    constexpr int WN = BN / 2;
    constexpr int FM = 4;
    constexpr int FN = WN / 16;
    constexpr int ACH = 16;       // A chunks of 1KB (128 rows x 64 k x 2B)
    constexpr int BCH = BN / 8;   // B chunks of 1KB

    __shared__ unsigned short sA[BM * 64];
    __shared__ unsigned short sB[BN * 64];

    const int tid = threadIdx.x;
    const int lane = tid & 63;
    const int wid = tid >> 6;
    const int wr = wid >> 1, wc = wid & 1;

    const int nbn = NN / BN;
    const int bm = blockIdx.x / nbn;
    const int bn = blockIdx.x % nbn;
    const int row0 = bm * BM;
    const int col0 = bn * BN;

    f32x4 acc[FM][FN];
#pragma unroll
    for (int m = 0; m < FM; ++m)
#pragma unroll
        for (int n = 0; n < FN; ++n) acc[m][n] = (f32x4){0.f, 0.f, 0.f, 0.f};

    const int st_r = lane >> 3;        // row within 8-row chunk
    const int st_k = (lane & 7) * 8;   // k element offset (16B granules)

    for (int seg = 0; seg < NSEG; ++seg) {
        const unsigned short* Ag = segs.a[seg];
        const unsigned short* Bg = segs.b[seg];
        for (int k0 = 0; k0 < KS; k0 += 64) {
            // stage A tile: rows [row0,row0+128), k [k0,k0+64)
            for (int c = wid; c < ACH; c += 4) {
                int gr = row0 + c * 8 + st_r;
                if (gr >= M) gr = 0;  // safe address; result unused
                const unsigned short* gp = Ag + (size_t)gr * KS + k0 + st_k;
                __builtin_amdgcn_global_load_lds(
                    (const __attribute__((address_space(1))) unsigned int*)gp,
                    (__attribute__((address_space(3))) unsigned int*)(sA + c * 512),
                    16, 0, 0);
            }
            // stage B tile: cols [col0,col0+BN), k [k0,k0+64)  (B is [NN][KS])
            for (int c = wid; c < BCH; c += 4) {
                int gn = col0 + c * 8 + st_r;
                const unsigned short* gp = Bg + (size_t)gn * KS + k0 + st_k;
                __builtin_amdgcn_global_load_lds(
                    (const __attribute__((address_space(1))) unsigned int*)gp,
                    (__attribute__((address_space(3))) unsigned int*)(sB + c * 512),
                    16, 0, 0);
            }
            __syncthreads();

#pragma unroll
            for (int ks = 0; ks < 2; ++ks) {
                bf16x8 af[FM], bfr[FN];
#pragma unroll
                for (int m = 0; m < FM; ++m) {
                    int rb = wr * 64 + m * 16 + (lane & 15);
                    af[m] = *(const bf16x8*)(sA + (size_t)rb * 64 + ks * 32 + (lane >> 4) * 8);
                }
#pragma unroll
                for (int n = 0; n < FN; ++n) {
                    int cb = wc * WN + n * 16 + (lane & 15);
                    bfr[n] = *(const bf16x8*)(sB + (size_t)cb * 64 + ks * 32 + (lane >> 4) * 8);
                }
#pragma unroll
                for (int m = 0; m < FM; ++m)
#pragma unroll
                    for (int n = 0; n < FN; ++n)
                        acc[m][n] = __builtin_amdgcn_mfma_f32_16x16x32_bf16(
                            af[m], bfr[n], acc[m][n], 0, 0, 0);
            }
            __syncthreads();
        }
    }

    // epilogue: C col = lane&15, row = (lane>>4)*4 + r  (per 16x16 fragment)
#pragma unroll
    for (int m = 0; m < FM; ++m) {
#pragma unroll
        for (int n = 0; n < FN; ++n) {
            int col = col0 + wc * WN + n * 16 + (lane & 15);
            float bb = bias[col];
#pragma unroll
            for (int r = 0; r < 4; ++r) {
                int row = row0 + wr * 64 + m * 16 + (lane >> 4) * 4 + r;
                if (row < M) {
                    float t = acc[m][n][r] + bb;
                    if (RELU) t = fmaxf(t, 0.f);
                    if (OUTMODE == 0) {
                        Cf[(size_t)row * NN + col] = t;
                    } else {
                        unsigned short hi = f2bf(t);
                        float lo = t - bf2f(hi);
                        Chi[(size_t)row * NN + col] = hi;
                        Clo[(size_t)row * NN + col] = f2bf(lo);
                    }
                }
            }
        }
    }
}

// ---------------------------------------------------------------------------
extern "C" void kernel_launch(void* const* d_in, const int* in_sizes, int n_in,
                              void* d_out, int out_size, void* d_ws, size_t ws_size,
                              hipStream_t stream) {
    const float* x   = (const float*)d_in[0];
    const void*  ei  = d_in[1];
    const float* W1l = (const float*)d_in[2];
    const float* b1  = (const float*)d_in[3];
    const float* W1r = (const float*)d_in[4];
    const float* W2l = (const float*)d_in[5];
    const float* b2  = (const float*)d_in[6];
    const float* W2r = (const float*)d_in[7];
    const float* Wc  = (const float*)d_in[8];
    const float* bc  = (const float*)d_in[9];
    float* out = (float*)d_out;

    const int N = in_sizes[0] / F_IN;     // 50000
    const int E = in_sizes[1] / 2;        // 800000

    typedef unsigned short u16;

    // ---- workspace carve-up (256B aligned) ----
    char* w = (char*)d_ws;
    size_t off = 0;
    auto carve = [&](size_t bytes) -> char* {
        char* p = w + off;
        off = (off + bytes + 255) & ~(size_t)255;
        return p;
    };
    int* ei32   = (int*)carve((size_t)2 * E * 4);
    int* cnt    = (int*)carve((size_t)N * 4);
    int* pos    = (int*)carve((size_t)N * 4);
    int* rowptr = (int*)carve((size_t)(N + 1) * 4);
    int* bsum   = (int*)carve(1024 * 4);
    int* boff   = (int*)carve(1024 * 4);
    int* flag   = (int*)carve(256);
    int* col    = (int*)carve((size_t)E * 4);

    u16* xhi    = (u16*)carve((size_t)N * F_IN * 2);     // 12.8MB
    u16* xlo    = (u16*)carve((size_t)N * F_IN * 2);     // contiguous with xhi
    u16* agghi  = (u16*)carve((size_t)N * 256 * 2);      // reused by both layers
    u16* agglo  = (u16*)carve((size_t)N * 256 * 2);
    u16* h1hi   = (u16*)carve((size_t)N * 256 * 2);
    u16* h1lo   = (u16*)carve((size_t)N * 256 * 2);
    u16* h2lo   = (u16*)carve((size_t)N * 256 * 2);
    u16* h2hi   = xhi;   // x is dead after gemm1; reuse xhi+xlo (25.6MB contiguous)

    u16* w1l_hi = (u16*)carve((size_t)F_IN * H1_DIM * 2);
    u16* w1l_lo = (u16*)carve((size_t)F_IN * H1_DIM * 2);
    u16* w1r_hi = (u16*)carve((size_t)F_IN * H1_DIM * 2);
    u16* w1r_lo = (u16*)carve((size_t)F_IN * H1_DIM * 2);
    u16* w2l_hi = (u16*)carve((size_t)H1_DIM * H2_DIM * 2);
    u16* w2l_lo = (u16*)carve((size_t)H1_DIM * H2_DIM * 2);
    u16* w2r_hi = (u16*)carve((size_t)H1_DIM * H2_DIM * 2);
    u16* w2r_lo = (u16*)carve((size_t)H1_DIM * H2_DIM * 2);
    u16* wc_hi  = (u16*)carve((size_t)H2_DIM * C_DIM * 2);
    u16* wc_lo  = (u16*)carve((size_t)H2_DIM * C_DIM * 2);
    (void)ws_size;

    hipMemsetAsync(cnt, 0, (size_t)N * 4, stream);
    hipMemsetAsync(pos, 0, (size_t)N * 4, stream);

    // ---- CSR build ----
    k_detect<<<1, 64, 0, stream>>>((const unsigned int*)ei, flag);
    k_convert<<<(2 * E + 255) / 256, 256, 0, stream>>>(ei, flag, ei32, 2 * E);
    k_degree<<<(E + 255) / 256, 256, 0, stream>>>(ei32, cnt, E);
    int nb = (N + 255) / 256;
    k_scan1<<<nb, 256, 0, stream>>>(cnt, rowptr, bsum, N);
    k_scan2<<<1, 1024, 0, stream>>>(bsum, boff, nb);
    k_scan3<<<nb, 256, 0, stream>>>(rowptr, boff, N, E);
    k_scatter<<<(E + 255) / 256, 256, 0, stream>>>(ei32, rowptr, pos, col, E);

    // ---- prep ----
    k_prep_x<<<((N * F_IN / 4) + 255) / 256, 256, 0, stream>>>(x, xhi, xlo, N * F_IN / 4);
    k_prep_wT<<<(F_IN * H1_DIM + 255) / 256, 256, 0, stream>>>(W1l, w1l_hi, w1l_lo, F_IN, H1_DIM);
    k_prep_wT<<<(F_IN * H1_DIM + 255) / 256, 256, 0, stream>>>(W1r, w1r_hi, w1r_lo, F_IN, H1_DIM);
    k_prep_wT<<<(H1_DIM * H2_DIM + 255) / 256, 256, 0, stream>>>(W2l, w2l_hi, w2l_lo, H1_DIM, H2_DIM);
    k_prep_wT<<<(H1_DIM * H2_DIM + 255) / 256, 256, 0, stream>>>(W2r, w2r_hi, w2r_lo, H1_DIM, H2_DIM);
    k_prep_wT<<<(H2_DIM * C_DIM + 255) / 256, 256, 0, stream>>>(Wc, wc_hi, wc_lo, H2_DIM, C_DIM);

    const int nbm = (N + 127) / 128;

    // ---- layer 1: h1 = relu(agg1@W1l + x@W1r + b1) ----
    k_agg1<<<(N + 3) / 4, 256, 0, stream>>>(x, rowptr, col, agghi, agglo, N);
    {
        Segs s;
        s.a[0] = agghi; s.b[0] = w1l_hi;
        s.a[1] = agglo; s.b[1] = w1l_hi;
        s.a[2] = agghi; s.b[2] = w1l_lo;
        s.a[3] = xhi;   s.b[3] = w1r_hi;
        s.a[4] = xlo;   s.b[4] = w1r_hi;
        s.a[5] = xhi;   s.b[5] = w1r_lo;
        k_mfma_gemm<128, 6, 128, true, 1><<<nbm * (H1_DIM / 128), 256, 0, stream>>>(
            s, b1, nullptr, h1hi, h1lo, N, H1_DIM);
    }

    // ---- layer 2: h2 = relu(agg2@W2l + h1@W2r + b2) ----
    k_agg2<<<(N + 3) / 4, 256, 0, stream>>>(h1hi, h1lo, rowptr, col, agghi, agglo, N);
    {
        Segs s;
        s.a[0] = agghi; s.b[0] = w2l_hi;
        s.a[1] = agglo; s.b[1] = w2l_hi;
        s.a[2] = agghi; s.b[2] = w2l_lo;
        s.a[3] = h1hi;  s.b[3] = w2r_hi;
        s.a[4] = h1lo;  s.b[4] = w2r_hi;
        s.a[5] = h1hi;  s.b[5] = w2r_lo;
        k_mfma_gemm<128, 6, 256, true, 1><<<nbm * (H2_DIM / 128), 256, 0, stream>>>(
            s, b2, nullptr, h2hi, h2lo, N, H2_DIM);
    }

    // ---- head: out = h2@Wc + bc ----
    {
        Segs s;
        s.a[0] = h2hi; s.b[0] = wc_hi;
        s.a[1] = h2lo; s.b[1] = wc_hi;
        s.a[2] = h2hi; s.b[2] = wc_lo;
        s.a[3] = nullptr; s.b[3] = nullptr;
        s.a[4] = nullptr; s.b[4] = nullptr;
        s.a[5] = nullptr; s.b[5] = nullptr;
        k_mfma_gemm<64, 3, 256, false, 0><<<nbm, 256, 0, stream>>>(
            s, bc, out, nullptr, nullptr, N, C_DIM);
    }
}

// Round 3
// 489.069 us; speedup vs baseline: 1.4623x; 1.1191x over previous
//
#include <hip/hip_runtime.h>
#include <hip/hip_bf16.h>

// ---------------------------------------------------------------------------
// GraphSAGE (2x SAGEConv mean + linear head), MI355X.
// GEMMs via split-bf16 MFMA (C = Ahi@Bhi + Alo@Bhi + Ahi@Blo, fp32 accum).
// Aggregations gather bf16-hi only (mean washes rounding error).
// ---------------------------------------------------------------------------

#define F_IN 128
#define H1_DIM 256
#define H2_DIM 256
#define C_DIM 64

typedef __attribute__((ext_vector_type(8))) short bf16x8;
typedef __attribute__((ext_vector_type(4))) float f32x4;

__device__ __forceinline__ unsigned short f2bf(float f) {
    unsigned u = __builtin_bit_cast(unsigned, f);
    u = (u + 0x7FFFu + ((u >> 16) & 1u)) >> 16;
    return (unsigned short)u;
}
__device__ __forceinline__ float bf2f(unsigned short h) {
    return __builtin_bit_cast(float, (unsigned)h << 16);
}

// ---------------- edge-index dtype detection -------------------------------
__global__ void k_detect(const unsigned int* __restrict__ ei, int* __restrict__ flag) {
    if (blockIdx.x == 0 && threadIdx.x == 0) {
        int is64 = 1;
        for (int i = 1; i < 256; i += 2) {
            if (ei[i] != 0u) { is64 = 0; break; }
        }
        *flag = is64;
    }
}

__device__ __forceinline__ int ei_at(const void* ei, const int* flag, long long idx) {
    return (*flag) ? (int)((const long long*)ei)[idx] : ((const int*)ei)[idx];
}

// ---------------- CSR build ------------------------------------------------
__global__ void k_degree(const void* __restrict__ ei, const int* __restrict__ flag,
                         int* __restrict__ cnt, int E) {
    int i = blockIdx.x * blockDim.x + threadIdx.x;
    if (i >= E) return;
    atomicAdd(&cnt[ei_at(ei, flag, (long long)E + i)], 1);
}

__global__ void k_scan1(const int* __restrict__ cnt, int* __restrict__ rowptr,
                        int* __restrict__ bsum, int n) {
    __shared__ int s[256];
    int i = blockIdx.x * 256 + threadIdx.x;
    int v = (i < n) ? cnt[i] : 0;
    s[threadIdx.x] = v;
    __syncthreads();
    for (int off = 1; off < 256; off <<= 1) {
        int t = (threadIdx.x >= off) ? s[threadIdx.x - off] : 0;
        __syncthreads();
        s[threadIdx.x] += t;
        __syncthreads();
    }
    if (i < n) rowptr[i] = s[threadIdx.x] - v;
    if (threadIdx.x == 255) bsum[blockIdx.x] = s[255];
}

__global__ void k_scan2(const int* __restrict__ bsum, int* __restrict__ boff, int nb) {
    __shared__ int s[1024];
    int t = threadIdx.x;
    int v = (t < nb) ? bsum[t] : 0;
    s[t] = v;
    __syncthreads();
    for (int off = 1; off < 1024; off <<= 1) {
        int u = (t >= off) ? s[t - off] : 0;
        __syncthreads();
        s[t] += u;
        __syncthreads();
    }
    if (t < nb) boff[t] = s[t] - v;
}

__global__ void k_scan3(int* __restrict__ rowptr, const int* __restrict__ boff,
                        int n, int total) {
    int i = blockIdx.x * 256 + threadIdx.x;
    if (i < n) rowptr[i] += boff[i >> 8];
    if (i == 0) rowptr[n] = total;
}

__global__ void k_scatter(const void* __restrict__ ei, const int* __restrict__ flag,
                          const int* __restrict__ rowptr, int* __restrict__ pos,
                          int* __restrict__ col, int E) {
    int i = blockIdx.x * blockDim.x + threadIdx.x;
    if (i >= E) return;
    int s = ei_at(ei, flag, i);
    int d = ei_at(ei, flag, (long long)E + i);
    int p = atomicAdd(&pos[d], 1);
    col[rowptr[d] + p] = s;
}

// ---------------- prep: fp32 -> bf16 hi/lo ---------------------------------
__global__ void k_prep_x(const float* __restrict__ x, unsigned short* __restrict__ hi,
                         unsigned short* __restrict__ lo, int n4) {
    int i = blockIdx.x * 256 + threadIdx.x;
    if (i >= n4) return;
    float4 v = ((const float4*)x)[i];
    ushort4 h, l;
    h.x = f2bf(v.x); l.x = f2bf(v.x - bf2f(h.x));
    h.y = f2bf(v.y); l.y = f2bf(v.y - bf2f(h.y));
    h.z = f2bf(v.z); l.z = f2bf(v.z - bf2f(h.z));
    h.w = f2bf(v.w); l.w = f2bf(v.w - bf2f(h.w));
    ((ushort4*)hi)[i] = h;
    ((ushort4*)lo)[i] = l;
}

// all 5 weight matrices in one launch: W [K][NN] fp32 -> hiT/loT [NN][K] bf16
struct WPrep {
    const float* W;
    unsigned short* hiT;
    unsigned short* loT;
    int K;
    int NN;
};

__global__ void k_prep_w(WPrep w0, WPrep w1, WPrep w2, WPrep w3, WPrep w4) {
    WPrep wp;
    switch (blockIdx.y) {
        case 0: wp = w0; break;
        case 1: wp = w1; break;
        case 2: wp = w2; break;
        case 3: wp = w3; break;
        default: wp = w4; break;
    }
    int total = wp.K * wp.NN;
    for (int i = blockIdx.x * 256 + threadIdx.x; i < total; i += gridDim.x * 256) {
        int k = i / wp.NN, n = i % wp.NN;
        float v = wp.W[i];
        unsigned short h = f2bf(v);
        wp.hiT[(size_t)n * wp.K + k] = h;
        wp.loT[(size_t)n * wp.K + k] = f2bf(v - bf2f(h));
    }
}

// ---------------- aggregation (gather hi-only) -----------------------------
// layer-1: mean of bf16 xhi rows (CH=128) -> bf16 hi/lo split of the mean
__global__ void k_agg1(const unsigned short* __restrict__ xhi,
                       const int* __restrict__ rowptr, const int* __restrict__ col,
                       unsigned short* __restrict__ mhi, unsigned short* __restrict__ mlo,
                       int n) {
    int w = blockIdx.x * 4 + (threadIdx.x >> 6);
    int lane = threadIdx.x & 63;
    if (w >= n) return;
    int beg = rowptr[w], end = rowptr[w + 1];
    float inv = 1.0f / fmaxf((float)(end - beg), 1.0f);
    float a0 = 0.f, a1 = 0.f;
    for (int j = beg; j < end; ++j) {
        ushort2 v = ((const ushort2*)(xhi + (size_t)col[j] * 128))[lane];
        a0 += bf2f(v.x);
        a1 += bf2f(v.y);
    }
    a0 *= inv; a1 *= inv;
    ushort2 h, l;
    h.x = f2bf(a0); l.x = f2bf(a0 - bf2f(h.x));
    h.y = f2bf(a1); l.y = f2bf(a1 - bf2f(h.y));
    ((ushort2*)(mhi + (size_t)w * 128))[lane] = h;
    ((ushort2*)(mlo + (size_t)w * 128))[lane] = l;
}

// layer-2: mean of bf16 h1hi rows (CH=256) -> bf16 hi/lo split of the mean
__global__ void k_agg2(const unsigned short* __restrict__ hhi,
                       const int* __restrict__ rowptr, const int* __restrict__ col,
                       unsigned short* __restrict__ mhi, unsigned short* __restrict__ mlo,
                       int n) {
    int w = blockIdx.x * 4 + (threadIdx.x >> 6);
    int lane = threadIdx.x & 63;
    if (w >= n) return;
    int beg = rowptr[w], end = rowptr[w + 1];
    float inv = 1.0f / fmaxf((float)(end - beg), 1.0f);
    float a0 = 0.f, a1 = 0.f, a2 = 0.f, a3 = 0.f;
    for (int j = beg; j < end; ++j) {
        ushort4 h = *(const ushort4*)(hhi + (size_t)col[j] * 256 + lane * 4);
        a0 += bf2f(h.x);
        a1 += bf2f(h.y);
        a2 += bf2f(h.z);
        a3 += bf2f(h.w);
    }
    a0 *= inv; a1 *= inv; a2 *= inv; a3 *= inv;
    ushort4 h, l;
    h.x = f2bf(a0); l.x = f2bf(a0 - bf2f(h.x));
    h.y = f2bf(a1); l.y = f2bf(a1 - bf2f(h.y));
    h.z = f2bf(a2); l.z = f2bf(a2 - bf2f(h.z));
    h.w = f2bf(a3); l.w = f2bf(a3 - bf2f(h.w));
    size_t ob = (size_t)w * 256 + lane * 4;
    *(ushort4*)(mhi + ob) = h;
    *(ushort4*)(mlo + ob) = l;
}

// ---------------- MFMA GEMM (segments of split-bf16 sources) ---------------
// C[M,NN] = act( sum_seg A_seg[M,KS] @ B_seg[KS,NN] + bias )
// A row-major [M][KS] bf16; B stored transposed [NN][KS] bf16.
// BM=128, BK=64, 256 threads = 4 waves as 2x2, wave tile 64 x (BN/2).
struct Segs {
    const unsigned short* a[6];
    const unsigned short* b[6];
};

template <int BN, int NSEG, int KS, bool RELU, int OUTMODE>
__global__ void k_mfma_gemm(Segs segs, const float* __restrict__ bias,
                            float* __restrict__ Cf, unsigned short* __restrict__ Chi,
                            unsigned short* __restrict__ Clo, int M, int NN) {
    constexpr int BM = 128;
    constexpr int WN = BN / 2;
    constexpr int FM = 4;
    constexpr int FN = WN / 16;
    constexpr int ACH = 16;       // A chunks of 1KB (128 rows x 64 k x 2B)
    constexpr int BCH = BN / 8;   // B chunks of 1KB

    __shared__ unsigned short sA[BM * 64];
    __shared__ unsigned short sB[BN * 64];

    const int tid = threadIdx.x;
    const int lane = tid & 63;
    const int wid = tid >> 6;
    const int wr = wid >> 1, wc = wid & 1;

    const int nbn = NN / BN;
    const int bm = blockIdx.x / nbn;
    const int bn = blockIdx.x % nbn;
    const int row0 = bm * BM;
    const int col0 = bn * BN;

    f32x4 acc[FM][FN];
#pragma unroll
    for (int m = 0; m < FM; ++m)
#pragma unroll
        for (int n = 0; n < FN; ++n) acc[m][n] = (f32x4){0.f, 0.f, 0.f, 0.f};

    const int st_r = lane >> 3;        // row within 8-row chunk
    const int st_k = (lane & 7) * 8;   // k element offset (16B granules)

    for (int seg = 0; seg < NSEG; ++seg) {
        const unsigned short* Ag = segs.a[seg];
        const unsigned short* Bg = segs.b[seg];
        for (int k0 = 0; k0 < KS; k0 += 64) {
            for (int c = wid; c < ACH; c += 4) {
                int gr = row0 + c * 8 + st_r;
                if (gr >= M) gr = 0;  // safe address; result unused
                const unsigned short* gp = Ag + (size_t)gr * KS + k0 + st_k;
                __builtin_amdgcn_global_load_lds(
                    (const __attribute__((address_space(1))) unsigned int*)gp,
                    (__attribute__((address_space(3))) unsigned int*)(sA + c * 512),
                    16, 0, 0);
            }
            for (int c = wid; c < BCH; c += 4) {
                int gn = col0 + c * 8 + st_r;
                const unsigned short* gp = Bg + (size_t)gn * KS + k0 + st_k;
                __builtin_amdgcn_global_load_lds(
                    (const __attribute__((address_space(1))) unsigned int*)gp,
                    (__attribute__((address_space(3))) unsigned int*)(sB + c * 512),
                    16, 0, 0);
            }
            __syncthreads();

#pragma unroll
            for (int ks = 0; ks < 2; ++ks) {
                bf16x8 af[FM], bfr[FN];
#pragma unroll
                for (int m = 0; m < FM; ++m) {
                    int rb = wr * 64 + m * 16 + (lane & 15);
                    af[m] = *(const bf16x8*)(sA + (size_t)rb * 64 + ks * 32 + (lane >> 4) * 8);
                }
#pragma unroll
                for (int n = 0; n < FN; ++n) {
                    int cb = wc * WN + n * 16 + (lane & 15);
                    bfr[n] = *(const bf16x8*)(sB + (size_t)cb * 64 + ks * 32 + (lane >> 4) * 8);
                }
#pragma unroll
                for (int m = 0; m < FM; ++m)
#pragma unroll
                    for (int n = 0; n < FN; ++n)
                        acc[m][n] = __builtin_amdgcn_mfma_f32_16x16x32_bf16(
                            af[m], bfr[n], acc[m][n], 0, 0, 0);
            }
            __syncthreads();
        }
    }

    // epilogue: C col = lane&15, row = (lane>>4)*4 + r  (per 16x16 fragment)
#pragma unroll
    for (int m = 0; m < FM; ++m) {
#pragma unroll
        for (int n = 0; n < FN; ++n) {
            int col = col0 + wc * WN + n * 16 + (lane & 15);
            float bb = bias[col];
#pragma unroll
            for (int r = 0; r < 4; ++r) {
                int row = row0 + wr * 64 + m * 16 + (lane >> 4) * 4 + r;
                if (row < M) {
                    float t = acc[m][n][r] + bb;
                    if (RELU) t = fmaxf(t, 0.f);
                    if (OUTMODE == 0) {
                        Cf[(size_t)row * NN + col] = t;
                    } else {
                        unsigned short hi = f2bf(t);
                        float lo = t - bf2f(hi);
                        Chi[(size_t)row * NN + col] = hi;
                        Clo[(size_t)row * NN + col] = f2bf(lo);
                    }
                }
            }
        }
    }
}

// ---------------------------------------------------------------------------
extern "C" void kernel_launch(void* const* d_in, const int* in_sizes, int n_in,
                              void* d_out, int out_size, void* d_ws, size_t ws_size,
                              hipStream_t stream) {
    const float* x   = (const float*)d_in[0];
    const void*  ei  = d_in[1];
    const float* W1l = (const float*)d_in[2];
    const float* b1  = (const float*)d_in[3];
    const float* W1r = (const float*)d_in[4];
    const float* W2l = (const float*)d_in[5];
    const float* b2  = (const float*)d_in[6];
    const float* W2r = (const float*)d_in[7];
    const float* Wc  = (const float*)d_in[8];
    const float* bc  = (const float*)d_in[9];
    float* out = (float*)d_out;

    const int N = in_sizes[0] / F_IN;     // 50000
    const int E = in_sizes[1] / 2;        // 800000

    typedef unsigned short u16;

    // ---- workspace carve-up (256B aligned) ----
    char* w = (char*)d_ws;
    size_t off = 0;
    auto carve = [&](size_t bytes) -> char* {
        char* p = w + off;
        off = (off + bytes + 255) & ~(size_t)255;
        return p;
    };
    int* cnt    = (int*)carve((size_t)N * 4);
    int* pos    = (int*)carve((size_t)N * 4);
    int* rowptr = (int*)carve((size_t)(N + 1) * 4);
    int* bsum   = (int*)carve(1024 * 4);
    int* boff   = (int*)carve(1024 * 4);
    int* flag   = (int*)carve(256);
    int* col    = (int*)carve((size_t)E * 4);

    u16* xhi    = (u16*)carve((size_t)N * F_IN * 2);
    u16* xlo    = (u16*)carve((size_t)N * F_IN * 2);   // contiguous with xhi
    u16* agghi  = (u16*)carve((size_t)N * 256 * 2);    // reused by both layers
    u16* agglo  = (u16*)carve((size_t)N * 256 * 2);
    u16* h1hi   = (u16*)carve((size_t)N * 256 * 2);
    u16* h1lo   = (u16*)carve((size_t)N * 256 * 2);
    u16* h2lo   = (u16*)carve((size_t)N * 256 * 2);
    u16* h2hi   = xhi;   // x dead after gemm1; xhi+xlo contiguous 25.6MB

    u16* w1l_hi = (u16*)carve((size_t)F_IN * H1_DIM * 2);
    u16* w1l_lo = (u16*)carve((size_t)F_IN * H1_DIM * 2);
    u16* w1r_hi = (u16*)carve((size_t)F_IN * H1_DIM * 2);
    u16* w1r_lo = (u16*)carve((size_t)F_IN * H1_DIM * 2);
    u16* w2l_hi = (u16*)carve((size_t)H1_DIM * H2_DIM * 2);
    u16* w2l_lo = (u16*)carve((size_t)H1_DIM * H2_DIM * 2);
    u16* w2r_hi = (u16*)carve((size_t)H1_DIM * H2_DIM * 2);
    u16* w2r_lo = (u16*)carve((size_t)H1_DIM * H2_DIM * 2);
    u16* wc_hi  = (u16*)carve((size_t)H2_DIM * C_DIM * 2);
    u16* wc_lo  = (u16*)carve((size_t)H2_DIM * C_DIM * 2);
    (void)ws_size;

    // zero cnt+pos (contiguous carves; zeroing pad is harmless)
    hipMemsetAsync(cnt, 0, (char*)rowptr - (char*)cnt, stream);

    // ---- CSR build (reads edge_index directly; dtype branch is uniform) ----
    k_detect<<<1, 64, 0, stream>>>((const unsigned int*)ei, flag);
    k_degree<<<(E + 255) / 256, 256, 0, stream>>>(ei, flag, cnt, E);
    int nb = (N + 255) / 256;
    k_scan1<<<nb, 256, 0, stream>>>(cnt, rowptr, bsum, N);
    k_scan2<<<1, 1024, 0, stream>>>(bsum, boff, nb);
    k_scan3<<<nb, 256, 0, stream>>>(rowptr, boff, N, E);
    k_scatter<<<(E + 255) / 256, 256, 0, stream>>>(ei, flag, rowptr, pos, col, E);

    // ---- prep ----
    k_prep_x<<<((N * F_IN / 4) + 255) / 256, 256, 0, stream>>>(x, xhi, xlo, N * F_IN / 4);
    {
        WPrep w0{W1l, w1l_hi, w1l_lo, F_IN, H1_DIM};
        WPrep w1{W1r, w1r_hi, w1r_lo, F_IN, H1_DIM};
        WPrep w2{W2l, w2l_hi, w2l_lo, H1_DIM, H2_DIM};
        WPrep w3{W2r, w2r_hi, w2r_lo, H1_DIM, H2_DIM};
        WPrep w4{Wc, wc_hi, wc_lo, H2_DIM, C_DIM};
        dim3 g(64, 5);
        k_prep_w<<<g, 256, 0, stream>>>(w0, w1, w2, w3, w4);
    }

    const int nbm = (N + 127) / 128;

    // ---- layer 1: h1 = relu(agg1@W1l + x@W1r + b1) ----
    k_agg1<<<(N + 3) / 4, 256, 0, stream>>>(xhi, rowptr, col, agghi, agglo, N);
    {
        Segs s;
        s.a[0] = agghi; s.b[0] = w1l_hi;
        s.a[1] = agglo; s.b[1] = w1l_hi;
        s.a[2] = agghi; s.b[2] = w1l_lo;
        s.a[3] = xhi;   s.b[3] = w1r_hi;
        s.a[4] = xlo;   s.b[4] = w1r_hi;
        s.a[5] = xhi;   s.b[5] = w1r_lo;
        k_mfma_gemm<128, 6, 128, true, 1><<<nbm * (H1_DIM / 128), 256, 0, stream>>>(
            s, b1, nullptr, h1hi, h1lo, N, H1_DIM);
    }

    // ---- layer 2: h2 = relu(agg2@W2l + h1@W2r + b2) ----
    k_agg2<<<(N + 3) / 4, 256, 0, stream>>>(h1hi, rowptr, col, agghi, agglo, N);
    {
        Segs s;
        s.a[0] = agghi; s.b[0] = w2l_hi;
        s.a[1] = agglo; s.b[1] = w2l_hi;
        s.a[2] = agghi; s.b[2] = w2l_lo;
        s.a[3] = h1hi;  s.b[3] = w2r_hi;
        s.a[4] = h1lo;  s.b[4] = w2r_hi;
        s.a[5] = h1hi;  s.b[5] = w2r_lo;
        k_mfma_gemm<128, 6, 256, true, 1><<<nbm * (H2_DIM / 128), 256, 0, stream>>>(
            s, b2, nullptr, h2hi, h2lo, N, H2_DIM);
    }

    // ---- head: out = h2@Wc + bc ----
    {
        Segs s;
        s.a[0] = h2hi; s.b[0] = wc_hi;
        s.a[1] = h2lo; s.b[1] = wc_hi;
        s.a[2] = h2hi; s.b[2] = wc_lo;
        s.a[3] = nullptr; s.b[3] = nullptr;
        s.a[4] = nullptr; s.b[4] = nullptr;
        s.a[5] = nullptr; s.b[5] = nullptr;
        k_mfma_gemm<64, 3, 256, false, 0><<<nbm, 256, 0, stream>>>(
            s, bc, out, nullptr, nullptr, N, C_DIM);
    }
}

// Round 4
// 415.345 us; speedup vs baseline: 1.7219x; 1.1775x over previous
//
#include <hip/hip_runtime.h>
#include <hip/hip_bf16.h>

// ---------------------------------------------------------------------------
// GraphSAGE (2x SAGEConv mean + linear head), MI355X.
// GEMMs via split-bf16 MFMA (C = Ahi@Bhi + Alo@Bhi + Ahi@Blo, fp32 accum).
// Aggregations gather bf16-hi only, multi-row-per-wave for MLP.
// ---------------------------------------------------------------------------

#define F_IN 128
#define H1_DIM 256
#define H2_DIM 256
#define C_DIM 64

typedef __attribute__((ext_vector_type(8))) short bf16x8;
typedef __attribute__((ext_vector_type(8))) unsigned short u16x8;
typedef __attribute__((ext_vector_type(4))) float f32x4;

__device__ __forceinline__ unsigned short f2bf(float f) {
    unsigned u = __builtin_bit_cast(unsigned, f);
    u = (u + 0x7FFFu + ((u >> 16) & 1u)) >> 16;
    return (unsigned short)u;
}
__device__ __forceinline__ float bf2f(unsigned short h) {
    return __builtin_bit_cast(float, (unsigned)h << 16);
}

// ---------------- edge-index dtype detection -------------------------------
__global__ void k_detect(const unsigned int* __restrict__ ei, int* __restrict__ flag) {
    if (blockIdx.x == 0 && threadIdx.x == 0) {
        int is64 = 1;
        for (int i = 1; i < 256; i += 2) {
            if (ei[i] != 0u) { is64 = 0; break; }
        }
        *flag = is64;
    }
}

__device__ __forceinline__ int ei_at(const void* ei, const int* flag, long long idx) {
    return (*flag) ? (int)((const long long*)ei)[idx] : ((const int*)ei)[idx];
}

// ---------------- CSR build ------------------------------------------------
__global__ void k_degree(const void* __restrict__ ei, const int* __restrict__ flag,
                         int* __restrict__ cnt, int E) {
    int i = blockIdx.x * blockDim.x + threadIdx.x;
    if (i >= E) return;
    atomicAdd(&cnt[ei_at(ei, flag, (long long)E + i)], 1);
}

__global__ void k_scan1(const int* __restrict__ cnt, int* __restrict__ rowptr,
                        int* __restrict__ bsum, int n) {
    __shared__ int s[256];
    int i = blockIdx.x * 256 + threadIdx.x;
    int v = (i < n) ? cnt[i] : 0;
    s[threadIdx.x] = v;
    __syncthreads();
    for (int off = 1; off < 256; off <<= 1) {
        int t = (threadIdx.x >= off) ? s[threadIdx.x - off] : 0;
        __syncthreads();
        s[threadIdx.x] += t;
        __syncthreads();
    }
    if (i < n) rowptr[i] = s[threadIdx.x] - v;
    if (threadIdx.x == 255) bsum[blockIdx.x] = s[255];
}

__global__ void k_scan2(const int* __restrict__ bsum, int* __restrict__ boff, int nb) {
    __shared__ int s[1024];
    int t = threadIdx.x;
    int v = (t < nb) ? bsum[t] : 0;
    s[t] = v;
    __syncthreads();
    for (int off = 1; off < 1024; off <<= 1) {
        int u = (t >= off) ? s[t - off] : 0;
        __syncthreads();
        s[t] += u;
        __syncthreads();
    }
    if (t < nb) boff[t] = s[t] - v;
}

__global__ void k_scan3(int* __restrict__ rowptr, const int* __restrict__ boff,
                        int n, int total) {
    int i = blockIdx.x * 256 + threadIdx.x;
    if (i < n) rowptr[i] += boff[i >> 8];
    if (i == 0) rowptr[n] = total;
}

__global__ void k_scatter(const void* __restrict__ ei, const int* __restrict__ flag,
                          const int* __restrict__ rowptr, int* __restrict__ pos,
                          int* __restrict__ col, int E) {
    int i = blockIdx.x * blockDim.x + threadIdx.x;
    if (i >= E) return;
    int s = ei_at(ei, flag, i);
    int d = ei_at(ei, flag, (long long)E + i);
    int p = atomicAdd(&pos[d], 1);
    col[rowptr[d] + p] = s;
}

// ---------------- prep: fp32 -> bf16 hi/lo ---------------------------------
__global__ void k_prep_x(const float* __restrict__ x, unsigned short* __restrict__ hi,
                         unsigned short* __restrict__ lo, int n4) {
    int i = blockIdx.x * 256 + threadIdx.x;
    if (i >= n4) return;
    float4 v = ((const float4*)x)[i];
    ushort4 h, l;
    h.x = f2bf(v.x); l.x = f2bf(v.x - bf2f(h.x));
    h.y = f2bf(v.y); l.y = f2bf(v.y - bf2f(h.y));
    h.z = f2bf(v.z); l.z = f2bf(v.z - bf2f(h.z));
    h.w = f2bf(v.w); l.w = f2bf(v.w - bf2f(h.w));
    ((ushort4*)hi)[i] = h;
    ((ushort4*)lo)[i] = l;
}

// all 5 weight matrices in one launch: W [K][NN] fp32 -> hiT/loT [NN][K] bf16
struct WPrep {
    const float* W;
    unsigned short* hiT;
    unsigned short* loT;
    int K;
    int NN;
};

__global__ void k_prep_w(WPrep w0, WPrep w1, WPrep w2, WPrep w3, WPrep w4) {
    WPrep wp;
    switch (blockIdx.y) {
        case 0: wp = w0; break;
        case 1: wp = w1; break;
        case 2: wp = w2; break;
        case 3: wp = w3; break;
        default: wp = w4; break;
    }
    int total = wp.K * wp.NN;
    for (int i = blockIdx.x * 256 + threadIdx.x; i < total; i += gridDim.x * 256) {
        int k = i / wp.NN, n = i % wp.NN;
        float v = wp.W[i];
        unsigned short h = f2bf(v);
        wp.hiT[(size_t)n * wp.K + k] = h;
        wp.loT[(size_t)n * wp.K + k] = f2bf(v - bf2f(h));
    }
}

// ---------------- aggregation (multi-row-per-wave gather) ------------------
// layer-1: rows are 128ch x 2B = 256B = 16 lanes x 16B. A wave covers 4 rows
// per iteration (quarter-wave each), 2x unrolled -> 8 gathers in flight.
__global__ void k_agg1(const unsigned short* __restrict__ xhi,
                       const int* __restrict__ rowptr, const int* __restrict__ col,
                       unsigned short* __restrict__ mhi, unsigned short* __restrict__ mlo,
                       int n) {
    int w = blockIdx.x * 4 + (threadIdx.x >> 6);
    int lane = threadIdx.x & 63;
    if (w >= n) return;
    int q = lane >> 4;            // quarter 0..3
    int ch = (lane & 15) * 8;     // 8 channels per lane
    int beg = rowptr[w], end = rowptr[w + 1];
    float inv = 1.0f / fmaxf((float)(end - beg), 1.0f);

    float a[8];
#pragma unroll
    for (int c = 0; c < 8; ++c) a[c] = 0.f;

    int j = beg + q;
    for (; j + 4 < end; j += 8) {
        int c0 = col[j], c1 = col[j + 4];
        u16x8 r0 = *(const u16x8*)(xhi + (size_t)c0 * 128 + ch);
        u16x8 r1 = *(const u16x8*)(xhi + (size_t)c1 * 128 + ch);
#pragma unroll
        for (int c = 0; c < 8; ++c) a[c] += bf2f(r0[c]) + bf2f(r1[c]);
    }
    if (j < end) {
        u16x8 r0 = *(const u16x8*)(xhi + (size_t)col[j] * 128 + ch);
#pragma unroll
        for (int c = 0; c < 8; ++c) a[c] += bf2f(r0[c]);
    }

    // combine quarters: after these, every lane has the full channel sums
#pragma unroll
    for (int c = 0; c < 8; ++c) a[c] += __shfl_xor(a[c], 16);
#pragma unroll
    for (int c = 0; c < 8; ++c) a[c] += __shfl_xor(a[c], 32);

    if (q < 2) {
        u16x8 o;
#pragma unroll
        for (int c = 0; c < 8; ++c) {
            float m = a[c] * inv;
            unsigned short h = f2bf(m);
            o[c] = (q == 0) ? h : f2bf(m - bf2f(h));
        }
        unsigned short* dst = (q == 0) ? mhi : mlo;
        *(u16x8*)(dst + (size_t)w * 128 + ch) = o;
    }
}

// layer-2: rows are 256ch x 2B = 512B = 32 lanes x 16B. A wave covers 2 rows
// per iteration (half-wave each), 2x unrolled -> 4 gathers in flight.
__global__ void k_agg2(const unsigned short* __restrict__ hhi,
                       const int* __restrict__ rowptr, const int* __restrict__ col,
                       unsigned short* __restrict__ mhi, unsigned short* __restrict__ mlo,
                       int n) {
    int w = blockIdx.x * 4 + (threadIdx.x >> 6);
    int lane = threadIdx.x & 63;
    if (w >= n) return;
    int h = lane >> 5;            // half 0..1
    int ch = (lane & 31) * 8;     // 8 channels per lane
    int beg = rowptr[w], end = rowptr[w + 1];
    float inv = 1.0f / fmaxf((float)(end - beg), 1.0f);

    float a[8];
#pragma unroll
    for (int c = 0; c < 8; ++c) a[c] = 0.f;

    int j = beg + h;
    for (; j + 2 < end; j += 4) {
        int c0 = col[j], c1 = col[j + 2];
        u16x8 r0 = *(const u16x8*)(hhi + (size_t)c0 * 256 + ch);
        u16x8 r1 = *(const u16x8*)(hhi + (size_t)c1 * 256 + ch);
#pragma unroll
        for (int c = 0; c < 8; ++c) a[c] += bf2f(r0[c]) + bf2f(r1[c]);
    }
    if (j < end) {
        u16x8 r0 = *(const u16x8*)(hhi + (size_t)col[j] * 256 + ch);
#pragma unroll
        for (int c = 0; c < 8; ++c) a[c] += bf2f(r0[c]);
    }

#pragma unroll
    for (int c = 0; c < 8; ++c) a[c] += __shfl_xor(a[c], 32);

    u16x8 o;
#pragma unroll
    for (int c = 0; c < 8; ++c) {
        float m = a[c] * inv;
        unsigned short hh = f2bf(m);
        o[c] = (h == 0) ? hh : f2bf(m - bf2f(hh));
    }
    unsigned short* dst = (h == 0) ? mhi : mlo;
    *(u16x8*)(dst + (size_t)w * 256 + ch) = o;
}

// ---------------- MFMA GEMM (segments of split-bf16 sources) ---------------
struct Segs {
    const unsigned short* a[6];
    const unsigned short* b[6];
};

template <int BN, int NSEG, int KS, bool RELU, int OUTMODE>
__global__ void k_mfma_gemm(Segs segs, const float* __restrict__ bias,
                            float* __restrict__ Cf, unsigned short* __restrict__ Chi,
                            unsigned short* __restrict__ Clo, int M, int NN) {
    constexpr int BM = 128;
    constexpr int WN = BN / 2;
    constexpr int FM = 4;
    constexpr int FN = WN / 16;
    constexpr int ACH = 16;       // A chunks of 1KB (128 rows x 64 k x 2B)
    constexpr int BCH = BN / 8;   // B chunks of 1KB

    __shared__ unsigned short sA[BM * 64];
    __shared__ unsigned short sB[BN * 64];

    const int tid = threadIdx.x;
    const int lane = tid & 63;
    const int wid = tid >> 6;
    const int wr = wid >> 1, wc = wid & 1;

    const int nbn = NN / BN;
    const int bm = blockIdx.x / nbn;
    const int bn = blockIdx.x % nbn;
    const int row0 = bm * BM;
    const int col0 = bn * BN;

    f32x4 acc[FM][FN];
#pragma unroll
    for (int m = 0; m < FM; ++m)
#pragma unroll
        for (int n = 0; n < FN; ++n) acc[m][n] = (f32x4){0.f, 0.f, 0.f, 0.f};

    const int st_r = lane >> 3;        // row within 8-row chunk
    const int st_k = (lane & 7) * 8;   // k element offset (16B granules)

    for (int seg = 0; seg < NSEG; ++seg) {
        const unsigned short* Ag = segs.a[seg];
        const unsigned short* Bg = segs.b[seg];
        for (int k0 = 0; k0 < KS; k0 += 64) {
            for (int c = wid; c < ACH; c += 4) {
                int gr = row0 + c * 8 + st_r;
                if (gr >= M) gr = 0;  // safe address; result unused
                const unsigned short* gp = Ag + (size_t)gr * KS + k0 + st_k;
                __builtin_amdgcn_global_load_lds(
                    (const __attribute__((address_space(1))) unsigned int*)gp,
                    (__attribute__((address_space(3))) unsigned int*)(sA + c * 512),
                    16, 0, 0);
            }
            for (int c = wid; c < BCH; c += 4) {
                int gn = col0 + c * 8 + st_r;
                const unsigned short* gp = Bg + (size_t)gn * KS + k0 + st_k;
                __builtin_amdgcn_global_load_lds(
                    (const __attribute__((address_space(1))) unsigned int*)gp,
                    (__attribute__((address_space(3))) unsigned int*)(sB + c * 512),
                    16, 0, 0);
            }
            __syncthreads();

#pragma unroll
            for (int ks = 0; ks < 2; ++ks) {
                bf16x8 af[FM], bfr[FN];
#pragma unroll
                for (int m = 0; m < FM; ++m) {
                    int rb = wr * 64 + m * 16 + (lane & 15);
                    af[m] = *(const bf16x8*)(sA + (size_t)rb * 64 + ks * 32 + (lane >> 4) * 8);
                }
#pragma unroll
                for (int n = 0; n < FN; ++n) {
                    int cb = wc * WN + n * 16 + (lane & 15);
                    bfr[n] = *(const bf16x8*)(sB + (size_t)cb * 64 + ks * 32 + (lane >> 4) * 8);
                }
#pragma unroll
                for (int m = 0; m < FM; ++m)
#pragma unroll
                    for (int n = 0; n < FN; ++n)
                        acc[m][n] = __builtin_amdgcn_mfma_f32_16x16x32_bf16(
                            af[m], bfr[n], acc[m][n], 0, 0, 0);
            }
            __syncthreads();
        }
    }

    // epilogue: C col = lane&15, row = (lane>>4)*4 + r  (per 16x16 fragment)
#pragma unroll
    for (int m = 0; m < FM; ++m) {
#pragma unroll
        for (int n = 0; n < FN; ++n) {
            int col = col0 + wc * WN + n * 16 + (lane & 15);
            float bb = bias[col];
#pragma unroll
            for (int r = 0; r < 4; ++r) {
                int row = row0 + wr * 64 + m * 16 + (lane >> 4) * 4 + r;
                if (row < M) {
                    float t = acc[m][n][r] + bb;
                    if (RELU) t = fmaxf(t, 0.f);
                    if (OUTMODE == 0) {
                        Cf[(size_t)row * NN + col] = t;
                    } else {
                        unsigned short hi = f2bf(t);
                        float lo = t - bf2f(hi);
                        Chi[(size_t)row * NN + col] = hi;
                        Clo[(size_t)row * NN + col] = f2bf(lo);
                    }
                }
            }
        }
    }
}

// ---------------------------------------------------------------------------
extern "C" void kernel_launch(void* const* d_in, const int* in_sizes, int n_in,
                              void* d_out, int out_size, void* d_ws, size_t ws_size,
                              hipStream_t stream) {
    const float* x   = (const float*)d_in[0];
    const void*  ei  = d_in[1];
    const float* W1l = (const float*)d_in[2];
    const float* b1  = (const float*)d_in[3];
    const float* W1r = (const float*)d_in[4];
    const float* W2l = (const float*)d_in[5];
    const float* b2  = (const float*)d_in[6];
    const float* W2r = (const float*)d_in[7];
    const float* Wc  = (const float*)d_in[8];
    const float* bc  = (const float*)d_in[9];
    float* out = (float*)d_out;

    const int N = in_sizes[0] / F_IN;     // 50000
    const int E = in_sizes[1] / 2;        // 800000

    typedef unsigned short u16;

    // ---- workspace carve-up (256B aligned) ----
    char* w = (char*)d_ws;
    size_t off = 0;
    auto carve = [&](size_t bytes) -> char* {
        char* p = w + off;
        off = (off + bytes + 255) & ~(size_t)255;
        return p;
    };
    int* cnt    = (int*)carve((size_t)N * 4);
    int* pos    = (int*)carve((size_t)N * 4);
    int* rowptr = (int*)carve((size_t)(N + 1) * 4);
    int* bsum   = (int*)carve(1024 * 4);
    int* boff   = (int*)carve(1024 * 4);
    int* flag   = (int*)carve(256);
    int* col    = (int*)carve((size_t)E * 4);

    u16* xhi    = (u16*)carve((size_t)N * F_IN * 2);
    u16* xlo    = (u16*)carve((size_t)N * F_IN * 2);   // contiguous with xhi
    u16* agghi  = (u16*)carve((size_t)N * 256 * 2);    // reused by both layers
    u16* agglo  = (u16*)carve((size_t)N * 256 * 2);
    u16* h1hi   = (u16*)carve((size_t)N * 256 * 2);
    u16* h1lo   = (u16*)carve((size_t)N * 256 * 2);
    u16* h2lo   = (u16*)carve((size_t)N * 256 * 2);
    u16* h2hi   = xhi;   // x dead after gemm1; xhi+xlo contiguous 25.6MB

    u16* w1l_hi = (u16*)carve((size_t)F_IN * H1_DIM * 2);
    u16* w1l_lo = (u16*)carve((size_t)F_IN * H1_DIM * 2);
    u16* w1r_hi = (u16*)carve((size_t)F_IN * H1_DIM * 2);
    u16* w1r_lo = (u16*)carve((size_t)F_IN * H1_DIM * 2);
    u16* w2l_hi = (u16*)carve((size_t)H1_DIM * H2_DIM * 2);
    u16* w2l_lo = (u16*)carve((size_t)H1_DIM * H2_DIM * 2);
    u16* w2r_hi = (u16*)carve((size_t)H1_DIM * H2_DIM * 2);
    u16* w2r_lo = (u16*)carve((size_t)H1_DIM * H2_DIM * 2);
    u16* wc_hi  = (u16*)carve((size_t)H2_DIM * C_DIM * 2);
    u16* wc_lo  = (u16*)carve((size_t)H2_DIM * C_DIM * 2);
    (void)ws_size;

    // zero cnt+pos (contiguous carves; zeroing pad is harmless)
    hipMemsetAsync(cnt, 0, (char*)rowptr - (char*)cnt, stream);

    // ---- CSR build (reads edge_index directly; dtype branch is uniform) ----
    k_detect<<<1, 64, 0, stream>>>((const unsigned int*)ei, flag);
    k_degree<<<(E + 255) / 256, 256, 0, stream>>>(ei, flag, cnt, E);
    int nb = (N + 255) / 256;
    k_scan1<<<nb, 256, 0, stream>>>(cnt, rowptr, bsum, N);
    k_scan2<<<1, 1024, 0, stream>>>(bsum, boff, nb);
    k_scan3<<<nb, 256, 0, stream>>>(rowptr, boff, N, E);
    k_scatter<<<(E + 255) / 256, 256, 0, stream>>>(ei, flag, rowptr, pos, col, E);

    // ---- prep ----
    k_prep_x<<<((N * F_IN / 4) + 255) / 256, 256, 0, stream>>>(x, xhi, xlo, N * F_IN / 4);
    {
        WPrep w0{W1l, w1l_hi, w1l_lo, F_IN, H1_DIM};
        WPrep w1{W1r, w1r_hi, w1r_lo, F_IN, H1_DIM};
        WPrep w2{W2l, w2l_hi, w2l_lo, H1_DIM, H2_DIM};
        WPrep w3{W2r, w2r_hi, w2r_lo, H1_DIM, H2_DIM};
        WPrep w4{Wc, wc_hi, wc_lo, H2_DIM, C_DIM};
        dim3 g(64, 5);
        k_prep_w<<<g, 256, 0, stream>>>(w0, w1, w2, w3, w4);
    }

    const int nbm = (N + 127) / 128;

    // ---- layer 1: h1 = relu(agg1@W1l + x@W1r + b1) ----
    k_agg1<<<(N + 3) / 4, 256, 0, stream>>>(xhi, rowptr, col, agghi, agglo, N);
    {
        Segs s;
        s.a[0] = agghi; s.b[0] = w1l_hi;
        s.a[1] = agglo; s.b[1] = w1l_hi;
        s.a[2] = agghi; s.b[2] = w1l_lo;
        s.a[3] = xhi;   s.b[3] = w1r_hi;
        s.a[4] = xlo;   s.b[4] = w1r_hi;
        s.a[5] = xhi;   s.b[5] = w1r_lo;
        k_mfma_gemm<128, 6, 128, true, 1><<<nbm * (H1_DIM / 128), 256, 0, stream>>>(
            s, b1, nullptr, h1hi, h1lo, N, H1_DIM);
    }

    // ---- layer 2: h2 = relu(agg2@W2l + h1@W2r + b2) ----
    k_agg2<<<(N + 3) / 4, 256, 0, stream>>>(h1hi, rowptr, col, agghi, agglo, N);
    {
        Segs s;
        s.a[0] = agghi; s.b[0] = w2l_hi;
        s.a[1] = agglo; s.b[1] = w2l_hi;
        s.a[2] = agghi; s.b[2] = w2l_lo;
        s.a[3] = h1hi;  s.b[3] = w2r_hi;
        s.a[4] = h1lo;  s.b[4] = w2r_hi;
        s.a[5] = h1hi;  s.b[5] = w2r_lo;
        k_mfma_gemm<128, 6, 256, true, 1><<<nbm * (H2_DIM / 128), 256, 0, stream>>>(
            s, b2, nullptr, h2hi, h2lo, N, H2_DIM);
    }

    // ---- head: out = h2@Wc + bc ----
    {
        Segs s;
        s.a[0] = h2hi; s.b[0] = wc_hi;
        s.a[1] = h2lo; s.b[1] = wc_hi;
        s.a[2] = h2hi; s.b[2] = wc_lo;
        s.a[3] = nullptr; s.b[3] = nullptr;
        s.a[4] = nullptr; s.b[4] = nullptr;
        s.a[5] = nullptr; s.b[5] = nullptr;
        k_mfma_gemm<64, 3, 256, false, 0><<<nbm, 256, 0, stream>>>(
            s, bc, out, nullptr, nullptr, N, C_DIM);
    }
}